// Round 6
// baseline (129.780 us; speedup 1.0000x reference)
//
#include <hip/hip_runtime.h>
#include <stdint.h>
#include <math.h>

// Problem constants (B=8192 rows, D=512 features)
#define Bn 8192
#define Dn 512
#define EPSN 1e-12f
#define EPSP 1e-6f
#define MARG 0.3f
#define QS 256.0f
#define ISQ (2.0f / 65536.0f)

// R23 = R22 with B (a_i8, i-side) taken OUT of LDS into per-lane registers,
// loaded directly from L2 (8 MB operands are L2-resident), double-buffered
// one tile ahead inside the counted-vmcnt ledger.
// R22 post-mortem: counted-lgkm overlap gained ~2us only. Root cause found
// by recounting poles per CU per K-tile: MFMA = 1306 cy, LDS = reads 96KB
// (4x A-dup + 2x B-dup) + 32KB staged writes = 1506 cy. The LDS PIPE is the
// larger pole - schedule tweaks (R20 thin, R21 fat, R22 counted-lgkm) could
// never beat it. Removing B from LDS cuts the pole to 64+16KB = 963 cy,
// making MFMA the pole. B-frags are per-wave private (lane-specific rows):
// LDS staging bought them nothing. Ledger's "B-out-of-LDS loses (R4/R7)"
// was the latency-bound 128^2 structure WITHOUT prefetch; here latency is
// covered by a full MFMA tile (T14) and the regime is LDS-throughput-bound.
// vmem ledger per tile kt: issue B(kt+1) x4, then A-stage(kt+2) x2;
// end-of-tile s_waitcnt vmcnt(2) drains A(kt+1)+B(kt+1), keeps A(kt+2) in
// flight (vmcnt retires in issue order). Tail: vmcnt(0) at kt=NKT-2.
// Kept verified: 256^2 tile, 8 waves (2j x 4i), 4-slot A ring, slot-XOR
// A staging + matching ds_read swizzle (BANK_CONFLICT=0 across 10 rounds),
// counted-lgkm MFMA pipeline (8 ds_read -> 4 groups), C^T epilogue with u32
// float keys + distributed atomicMax. B global-chunk algebra reproduces the
// swizzled-LDS result exactly: chunk q of row wc*64+nt*16+m16.
// Ledger: occupancy lever exhausted (R2/R5/R6), fp8 mfma_scale spills (R9),
// i8 2xK wins (R11), packed partials kill write amplification (R14/R15),
// algebraic neg^2 kills gather (R16), single-address atomics +100us (R5),
// ticket+fence +20us (R10), cooperative launch no-ops (R12), epilogue-VALU
// fixed by C^T+u32 keys (R18), sync granularity exhausted (R20/R21/R22):
// K2 is LDS-pipe-bound -> this round removes 1/3 of LDS traffic.

#define TKB 64                 // k bytes per K-tile
#define NKT (Dn / TKB)         // 8 K-tiles

typedef int   int4v __attribute__((ext_vector_type(4)));
typedef float f32x4 __attribute__((ext_vector_type(4)));

// async global->LDS, 16B per lane; LDS dest is wave-uniform base + lane*16
__device__ __forceinline__ void async16(const void* g, void* l) {
    __builtin_amdgcn_global_load_lds(
        (const __attribute__((address_space(1))) void*)g,
        (__attribute__((address_space(3))) void*)l,
        16, 0, 0);
}

// monotonic float->u32 key: key(a) > key(b) iff a > b (finite floats).
// Any finite score's key is nonzero, so 0 is the atomicMax identity.
__device__ __forceinline__ unsigned key32(float s) {
    union { float f; unsigned u; } c; c.f = s;
    return (c.u & 0x80000000u) ? ~c.u : (c.u | 0x80000000u);
}
__device__ __forceinline__ float unkey32(unsigned k) {
    union { unsigned u; float f; } c;
    c.u = (k & 0x80000000u) ? (k ^ 0x80000000u) : ~k;
    return c.f;
}

// ---------------------------------------------------------------------------
// K1: one wave per row pair (a_i, p_i): L2-normalize both -> i8 rows (x256,
// RNE, clamp +-127), column term c[j] = -sp2[j] + 2*eps*sp[j], rowconst[i] =
// pos2 - sa2 - 2*eps*sa - D*eps^2 + MARGIN (exact fp32), and rowmax[i] = 0.
// ---------------------------------------------------------------------------
__global__ __launch_bounds__(256) void k_normalize(
    const float* __restrict__ x,
    uint8_t* __restrict__ a_i8, uint8_t* __restrict__ p_i8,
    float* __restrict__ cterm, float* __restrict__ rowconst,
    unsigned* __restrict__ rowmax)
{
    const int wave = threadIdx.x >> 6;
    const int lane = threadIdx.x & 63;
    const int i = blockIdx.x * 4 + wave;   // 0..8191

    const float* srcA = x + (size_t)i * (2 * Dn) + lane * 8;
    const float* srcP = srcA + Dn;
    float4 a0 = ((const float4*)srcA)[0];
    float4 a1 = ((const float4*)srcA)[1];
    float4 p0 = ((const float4*)srcP)[0];
    float4 p1 = ((const float4*)srcP)[1];
    float va[8] = {a0.x, a0.y, a0.z, a0.w, a1.x, a1.y, a1.z, a1.w};
    float vp[8] = {p0.x, p0.y, p0.z, p0.w, p1.x, p1.y, p1.z, p1.w};

    float ssa = 0.f, ssp = 0.f;
#pragma unroll
    for (int j = 0; j < 8; ++j) { ssa += va[j] * va[j]; ssp += vp[j] * vp[j]; }
#pragma unroll
    for (int m = 1; m < 64; m <<= 1) {
        ssa += __shfl_xor(ssa, m);
        ssp += __shfl_xor(ssp, m);
    }
    const float sa = 1.0f / fmaxf(sqrtf(ssa), EPSN);
    const float sp = 1.0f / fmaxf(sqrtf(ssp), EPSN);

    float oa[8], op[8];
    float s1p = 0.f, s2p = 0.f, s1a = 0.f, s2a = 0.f, pos = 0.f;
#pragma unroll
    for (int j = 0; j < 8; ++j) {
        oa[j] = va[j] * sa;
        op[j] = vp[j] * sp;
        s1p += op[j]; s2p += op[j] * op[j];
        s1a += oa[j]; s2a += oa[j] * oa[j];
        const float u = oa[j] - op[j] + EPSP;
        pos += u * u;
    }

    uint64_t pka = 0, pkp = 0;
#pragma unroll
    for (int j = 0; j < 8; ++j) {
        int qa = (int)rintf(oa[j] * QS);
        int qp = (int)rintf(op[j] * QS);
        qa = qa > 127 ? 127 : (qa < -127 ? -127 : qa);
        qp = qp > 127 ? 127 : (qp < -127 ? -127 : qp);
        pka |= (uint64_t)(uint8_t)qa << (8 * j);
        pkp |= (uint64_t)(uint8_t)qp << (8 * j);
    }
    *(uint64_t*)(a_i8 + (size_t)i * Dn + lane * 8) = pka;
    *(uint64_t*)(p_i8 + (size_t)i * Dn + lane * 8) = pkp;

#pragma unroll
    for (int m = 1; m < 64; m <<= 1) {
        s1p += __shfl_xor(s1p, m);
        s2p += __shfl_xor(s2p, m);
        s1a += __shfl_xor(s1a, m);
        s2a += __shfl_xor(s2a, m);
        pos += __shfl_xor(pos, m);
    }
    if (lane == 0) {
        cterm[i] = -s2p + 2.0f * EPSP * s1p;
        rowconst[i] = pos - s2a - 2.0f * EPSP * s1a
                      - (float)Dn * EPSP * EPSP + MARG;
        rowmax[i] = 0u;              // atomicMax identity (poisoned otherwise)
    }
}

// ---------------------------------------------------------------------------
// K2: i8 MFMA GEMM, 256^2 tile. A (p rows) via 4-slot LDS ring; B (a rows)
// via per-lane register double-buffer direct from L2. Counted vmcnt + lgkm.
// acc = C^T (j in-lane, i across lanes); fused per-i max epilogue.
// ---------------------------------------------------------------------------
__global__ __launch_bounds__(512, 2) void k_gemm_argmax(
    const uint8_t* __restrict__ a_i8, const uint8_t* __restrict__ p_i8,
    const float* __restrict__ cterm,
    unsigned* __restrict__ rowmax)
{
    __shared__ __align__(16) uint8_t As[4][256 * TKB];   // 64 KB, p rows (j)
    __shared__ unsigned smx[2][256];                     // wr-half combine

    const int t = threadIdx.x;          // 0..511
    const int wave = t >> 6;            // 0..7
    const int lane = t & 63;
    const int q = lane >> 4;            // 0..3  (k-chunk; C/D row = q*4+v)
    const int m16 = lane & 15;          // 0..15 (C/D col)
    const int wr = wave >> 2;           // j half (0..1)
    const int wc = wave & 3;            // i quarter (0..3)
    const int j0 = blockIdx.y * 256;    // p-row base
    const int i0 = blockIdx.x * 256;    // a-row base (rowmax index)

    // ---- A staging: per K-tile = 2 insts/thread (half0 rows 0-127, half1
    // rows 128-255). Thread t covers chunk t of the half: row = t>>2, LDS
    // slot t&3 holds global k-chunk (t&3)^((row>>1)&3) (slot-XOR swizzle).
    const int rr = t >> 2;                               // 0..127
    const int gg = ((t & 3) ^ ((t >> 3) & 3)) * 16;      // byte slot in k-tile
    const uint8_t* gA0 = p_i8 + (size_t)(j0 + rr) * Dn + gg;
    const uint8_t* gA1 = p_i8 + (size_t)(j0 + 128 + rr) * Dn + gg;
    const int ldsOff = wave * 1024;     // + HW lane*16; halves at +8192

    // ---- A fragment read base: slot = q ^ ((m16>>1)&3) (matches stage XOR)
    const int sl = (q ^ ((m16 >> 1) & 3)) * 16;
    const int aOff = (wr * 128 + m16) * TKB + sl;        // + mt*1024

    // ---- B register loads, direct from L2: lane reads global k-chunk q of
    // row i0 + wc*64 + nt*16 + m16 (exactly what the swizzled LDS read
    // delivered in R22). 16 fully-consumed cache lines per wave-load.
    const uint8_t* gBreg = a_i8 + (size_t)(i0 + wc * 64 + m16) * Dn + q * 16;

    auto stageA = [&](int slot, int kb) {        // 2 vmem ops
        async16(gA0 + kb, &As[slot][ldsOff]);
        async16(gA1 + kb, &As[slot][8192 + ldsOff]);
    };

    int4v acc[8][4];
#pragma unroll
    for (int a = 0; a < 8; ++a)
#pragma unroll
        for (int b = 0; b < 4; ++b) acc[a][b] = (int4v){0, 0, 0, 0};

    int4v bfA[4], bfB[4];   // B double-buffer (static-indexed after unroll)

    // prologue. vmem issue order: A(0) x2, B(0) x4, A(1) x2 -> vmcnt(2)
    // drains A(0)+B(0), keeps A(1) in flight.
    stageA(0, 0);
#pragma unroll
    for (int nt = 0; nt < 4; ++nt)
        bfA[nt] = *(const int4v*)(gBreg + nt * 16 * Dn);
    __builtin_amdgcn_sched_barrier(0);
    stageA(1, TKB);
    __builtin_amdgcn_sched_barrier(0);
    asm volatile("s_waitcnt vmcnt(2)" ::: "memory");
    __builtin_amdgcn_s_barrier();

#pragma unroll
    for (int kt = 0; kt < NKT; ++kt) {
        const int slot = kt & 3;
        const uint8_t* pa = &As[slot][aOff];
        int4v* bfc = (kt & 1) ? bfB : bfA;   // constant after full unroll
        int4v* bfn = (kt & 1) ? bfA : bfB;

        // ---- issue next tile's B loads (4 vmem), then A stage kt+2 (2 vmem)
        if (kt + 1 < NKT) {
#pragma unroll
            for (int nt = 0; nt < 4; ++nt)
                bfn[nt] = *(const int4v*)(gBreg + nt * 16 * Dn + (kt + 1) * TKB);
        }
        __builtin_amdgcn_sched_barrier(0);
        if (kt + 2 < NKT) stageA((kt + 2) & 3, (kt + 2) * TKB);
        __builtin_amdgcn_sched_barrier(0);

        // ---- issue all 8 A ds_read_b128 in PINNED order (DS completes
        // in-order per wave -> counted lgkm waits release exact subsets).
        int4v af[8];
        af[0] = *(const int4v*)(pa + 0 * 1024);
        af[1] = *(const int4v*)(pa + 1 * 1024);
        __builtin_amdgcn_sched_barrier(0);
        af[2] = *(const int4v*)(pa + 2 * 1024);
        af[3] = *(const int4v*)(pa + 3 * 1024);
        __builtin_amdgcn_sched_barrier(0);
        af[4] = *(const int4v*)(pa + 4 * 1024);
        af[5] = *(const int4v*)(pa + 5 * 1024);
        __builtin_amdgcn_sched_barrier(0);
        af[6] = *(const int4v*)(pa + 6 * 1024);
        af[7] = *(const int4v*)(pa + 7 * 1024);
        __builtin_amdgcn_sched_barrier(0);

        // ---- pipelined MFMA: each counted wait releases one 8-MFMA group
        // while the remaining ds_reads stream underneath.
        asm volatile("s_waitcnt lgkmcnt(6)" ::: "memory");
        __builtin_amdgcn_sched_barrier(0);   // rule 18
        __builtin_amdgcn_s_setprio(1);
#pragma unroll
        for (int nt = 0; nt < 4; ++nt)
            acc[0][nt] = __builtin_amdgcn_mfma_i32_16x16x64_i8(
                af[0], bfc[nt], acc[0][nt], 0, 0, 0);
#pragma unroll
        for (int nt = 0; nt < 4; ++nt)
            acc[1][nt] = __builtin_amdgcn_mfma_i32_16x16x64_i8(
                af[1], bfc[nt], acc[1][nt], 0, 0, 0);

        asm volatile("s_waitcnt lgkmcnt(4)" ::: "memory");
        __builtin_amdgcn_sched_barrier(0);
#pragma unroll
        for (int nt = 0; nt < 4; ++nt)
            acc[2][nt] = __builtin_amdgcn_mfma_i32_16x16x64_i8(
                af[2], bfc[nt], acc[2][nt], 0, 0, 0);
#pragma unroll
        for (int nt = 0; nt < 4; ++nt)
            acc[3][nt] = __builtin_amdgcn_mfma_i32_16x16x64_i8(
                af[3], bfc[nt], acc[3][nt], 0, 0, 0);

        asm volatile("s_waitcnt lgkmcnt(2)" ::: "memory");
        __builtin_amdgcn_sched_barrier(0);
#pragma unroll
        for (int nt = 0; nt < 4; ++nt)
            acc[4][nt] = __builtin_amdgcn_mfma_i32_16x16x64_i8(
                af[4], bfc[nt], acc[4][nt], 0, 0, 0);
#pragma unroll
        for (int nt = 0; nt < 4; ++nt)
            acc[5][nt] = __builtin_amdgcn_mfma_i32_16x16x64_i8(
                af[5], bfc[nt], acc[5][nt], 0, 0, 0);

        asm volatile("s_waitcnt lgkmcnt(0)" ::: "memory");
        __builtin_amdgcn_sched_barrier(0);
#pragma unroll
        for (int nt = 0; nt < 4; ++nt)
            acc[6][nt] = __builtin_amdgcn_mfma_i32_16x16x64_i8(
                af[6], bfc[nt], acc[6][nt], 0, 0, 0);
#pragma unroll
        for (int nt = 0; nt < 4; ++nt)
            acc[7][nt] = __builtin_amdgcn_mfma_i32_16x16x64_i8(
                af[7], bfc[nt], acc[7][nt], 0, 0, 0);
        __builtin_amdgcn_s_setprio(0);

        // ---- counted drain before the ring barrier. vmcnt retires in issue
        // order; queue (oldest first): A(kt+1) x2, B(kt+1) x4, A(kt+2) x2.
        // vmcnt(2) drains A(kt+1) [needed by next tile's ds_reads] and
        // B(kt+1) [needed by next tile's MFMAs], keeps A(kt+2) in flight.
        if (kt + 2 < NKT)
            asm volatile("s_waitcnt vmcnt(2)" ::: "memory");
        else if (kt + 2 == NKT)
            asm volatile("s_waitcnt vmcnt(0)" ::: "memory");
        if (kt + 1 < NKT) __builtin_amdgcn_s_barrier();
    }

    // ---- epilogue: acc[mt][nt][v] = idot(j, i) with
    //   j = j0 + wr*128 + mt*16 + q*4 + v   (32 in-lane candidates per nt)
    //   i = i0 + wc*64  + nt*16 + m16
    f32x4 cj[8];
#pragma unroll
    for (int mt = 0; mt < 8; ++mt)   // broadcast loads, L2-resident 32 KB
        cj[mt] = *(const f32x4*)(cterm + j0 + wr * 128 + mt * 16 + q * 4);

    unsigned kv[4];
    const bool diag = (i0 == j0);    // 32 of 1024 blocks
    if (!diag) {
#pragma unroll
        for (int nt = 0; nt < 4; ++nt) {
            float mx = -3.4e38f;
#pragma unroll
            for (int mt = 0; mt < 8; ++mt)
#pragma unroll
                for (int v = 0; v < 4; ++v)
                    mx = fmaxf(mx, ISQ * (float)acc[mt][nt][v] + cj[mt][v]);
            kv[nt] = key32(mx);
        }
    } else {
#pragma unroll
        for (int nt = 0; nt < 4; ++nt) {
            // j==i  <=>  mt*16+v == dtarget (at most one of the 32)
            const int dtarget = wc * 64 + nt * 16 + m16 - wr * 128 - q * 4;
            float mx = -3.4e38f;
#pragma unroll
            for (int mt = 0; mt < 8; ++mt)
#pragma unroll
                for (int v = 0; v < 4; ++v) {
                    const float sc = ISQ * (float)acc[mt][nt][v] + cj[mt][v];
                    mx = (mt * 16 + v == dtarget) ? mx : fmaxf(mx, sc);
                }
            kv[nt] = key32(mx);
        }
    }

    // combine the 4 q-groups (same i, different j): masks 16, 32
#pragma unroll
    for (int nt = 0; nt < 4; ++nt) {
#pragma unroll
        for (int msk = 16; msk < 64; msk <<= 1) {
            const unsigned o = (unsigned)__shfl_xor((int)kv[nt], msk);
            kv[nt] = o > kv[nt] ? o : kv[nt];
        }
    }
    if (lane < 16) {   // q==0 lanes hold the reduced keys
#pragma unroll
        for (int nt = 0; nt < 4; ++nt)
            smx[wr][wc * 64 + nt * 16 + m16] = kv[nt];
    }
    __syncthreads();
    if (t < 256) {
        const unsigned k0 = smx[0][t];
        const unsigned k1 = smx[1][t];
        // distributed per-row max: 32 blocks contend per address (order-
        // independent -> deterministic), 8192 addresses total.
        atomicMax(&rowmax[i0 + t], k0 > k1 ? k0 : k1);
    }
}

// ---------------------------------------------------------------------------
// K3: single block - loss = mean(relu(rowconst[i] + score_max[i])).
// Reads 64 KB; deterministic fixed-order sums.
// ---------------------------------------------------------------------------
__global__ __launch_bounds__(1024) void k_final(
    const unsigned* __restrict__ rowmax,
    const float* __restrict__ rowconst,
    float* __restrict__ out)
{
    __shared__ float smf[16];
    float s = 0.f;
    for (int k = threadIdx.x; k < Bn; k += 1024)
        s += fmaxf(rowconst[k] + unkey32(rowmax[k]), 0.f);
#pragma unroll
    for (int msk = 1; msk < 64; msk <<= 1) s += __shfl_xor(s, msk);
    if ((threadIdx.x & 63) == 0) smf[threadIdx.x >> 6] = s;
    __syncthreads();
    if (threadIdx.x == 0) {
        float tot = 0.f;
#pragma unroll
        for (int w = 0; w < 16; ++w) tot += smf[w];
        out[0] = tot * (1.0f / Bn);
    }
}

extern "C" void kernel_launch(void* const* d_in, const int* in_sizes, int n_in,
                              void* d_out, int out_size, void* d_ws, size_t ws_size,
                              hipStream_t stream)
{
    const float* x = (const float*)d_in[0];
    char* ws = (char*)d_ws;
    // workspace layout (bytes):
    uint8_t*  a_i8     = (uint8_t*)(ws + 0);         // 4 MB
    uint8_t*  p_i8     = (uint8_t*)(ws + 4194304);   // 4 MB
    float*    cterm    = (float*)(ws + 8388608);     // 32 KB
    float*    rowconst = (float*)(ws + 8421376);     // 32 KB
    unsigned* rowmax   = (unsigned*)(ws + 8454144);  // 32 KB (total ~8.5 MB)
    float*    out      = (float*)d_out;

    k_normalize<<<2048, 256, 0, stream>>>(x, a_i8, p_i8, cterm, rowconst, rowmax);
    k_gemm_argmax<<<dim3(Bn / 256, Bn / 256), 512, 0, stream>>>(
        a_i8, p_i8, cterm, rowmax);
    k_final<<<1, 1024, 0, stream>>>(rowmax, rowconst, out);
}

// Round 7
// 114.625 us; speedup vs baseline: 1.1322x; 1.1322x over previous
//
#include <hip/hip_runtime.h>
#include <stdint.h>
#include <math.h>

// Problem constants (B=8192 rows, D=512 features)
#define Bn 8192
#define Dn 512
#define EPSN 1e-12f
#define EPSP 1e-6f
#define MARG 0.3f
#define QS 256.0f
#define ISQ (2.0f / 65536.0f)

// R24 = R22 (B back in LDS) + register-level fragment prefetch one tile
// ahead: during tile kt's 32-MFMA cluster, tile kt+1's 12 ds_read_b128 are
// issued into the other half of a static frag double-buffer; tile kt+1 opens
// with a single lgkmcnt(0) that is then already satisfied. The CU's single
// LDS pipe (96 wave-reads/tile ~ 1152cy round-robin) runs UNDER the matrix
// pipe (1306cy) instead of in front of it.
// R23 post-mortem: B-direct-from-L2 REGRESSED (43->59.6us). Vector-memory
// path (~56 B/cy/CU L2 share) is SLOWER than the LDS pipe (~85 B/cy) and
// dropping B from LDS killed cross-wr sharing (2x B VMEM bytes). Reverted.
// R20/R21/R22 were neutral because all kept read-issue->wait->MFMA inside
// one tile: every tile pays the ~500cy LDS round-robin lead-in serially.
// Consequence of prefetch: staging must land one tile earlier -> stage-ahead
// 3 (prologue stages 0,1,2; tile kt issues stage(kt+3); end-of-tile vmcnt(4)
// drains stage(kt+2) for the next tile's prefetch; vmcnt(0) at kt=5 drains
// stage(7); kt=6,7 need no vmem wait). Ring-slot safety: writer of slot
// (kt+3)&3=(kt-1)&3 issues in tile kt; its readers (frags(kt-1) prefetch,
// issued tile kt-2) drained at tile kt-1 top, >=1 barrier before the writer.
// Frag dbuf is static-indexed via explicit macro expansion (rule 20);
// VGPR ~250, __launch_bounds__(512,2) pins <=256.
// Kept verified: 256^2 tile, 8 waves (2j x 4i), slot-XOR staging + matching
// ds_read swizzle (BANK_CONFLICT=0 across 11 rounds), C^T epilogue with u32
// float keys + distributed atomicMax.
// Ledger: occupancy lever exhausted (R2/R5/R6), B-out-of-LDS loses (R4/R7,
// re-confirmed R23: VMEM pipe < LDS pipe), fp8 mfma_scale spills (R9), i8
// 2xK wins (R11), packed partials kill write amplification (R14/R15),
// algebraic neg^2 kills gather (R16), single-address atomics +100us (R5),
// ticket+fence +20us (R10), cooperative launch no-ops (R12), epilogue-VALU
// fixed by C^T+u32 keys (R18), same-tile sync granularity exhausted
// (R20/R21/R22) -> cross-tile register prefetch is this round's lever.

#define TKB 64                 // k bytes per K-tile
#define NKT (Dn / TKB)         // 8 K-tiles

typedef int   int4v __attribute__((ext_vector_type(4)));
typedef float f32x4 __attribute__((ext_vector_type(4)));

// async global->LDS, 16B per lane; LDS dest is wave-uniform base + lane*16
__device__ __forceinline__ void async16(const void* g, void* l) {
    __builtin_amdgcn_global_load_lds(
        (const __attribute__((address_space(1))) void*)g,
        (__attribute__((address_space(3))) void*)l,
        16, 0, 0);
}

// monotonic float->u32 key: key(a) > key(b) iff a > b (finite floats).
// Any finite score's key is nonzero, so 0 is the atomicMax identity.
__device__ __forceinline__ unsigned key32(float s) {
    union { float f; unsigned u; } c; c.f = s;
    return (c.u & 0x80000000u) ? ~c.u : (c.u | 0x80000000u);
}
__device__ __forceinline__ float unkey32(unsigned k) {
    union { unsigned u; float f; } c;
    c.u = (k & 0x80000000u) ? (k ^ 0x80000000u) : ~k;
    return c.f;
}

// ---------------------------------------------------------------------------
// K1: one wave per row pair (a_i, p_i): L2-normalize both -> i8 rows (x256,
// RNE, clamp +-127), column term c[j] = -sp2[j] + 2*eps*sp[j], rowconst[i] =
// pos2 - sa2 - 2*eps*sa - D*eps^2 + MARGIN (exact fp32), and rowmax[i] = 0.
// ---------------------------------------------------------------------------
__global__ __launch_bounds__(256) void k_normalize(
    const float* __restrict__ x,
    uint8_t* __restrict__ a_i8, uint8_t* __restrict__ p_i8,
    float* __restrict__ cterm, float* __restrict__ rowconst,
    unsigned* __restrict__ rowmax)
{
    const int wave = threadIdx.x >> 6;
    const int lane = threadIdx.x & 63;
    const int i = blockIdx.x * 4 + wave;   // 0..8191

    const float* srcA = x + (size_t)i * (2 * Dn) + lane * 8;
    const float* srcP = srcA + Dn;
    float4 a0 = ((const float4*)srcA)[0];
    float4 a1 = ((const float4*)srcA)[1];
    float4 p0 = ((const float4*)srcP)[0];
    float4 p1 = ((const float4*)srcP)[1];
    float va[8] = {a0.x, a0.y, a0.z, a0.w, a1.x, a1.y, a1.z, a1.w};
    float vp[8] = {p0.x, p0.y, p0.z, p0.w, p1.x, p1.y, p1.z, p1.w};

    float ssa = 0.f, ssp = 0.f;
#pragma unroll
    for (int j = 0; j < 8; ++j) { ssa += va[j] * va[j]; ssp += vp[j] * vp[j]; }
#pragma unroll
    for (int m = 1; m < 64; m <<= 1) {
        ssa += __shfl_xor(ssa, m);
        ssp += __shfl_xor(ssp, m);
    }
    const float sa = 1.0f / fmaxf(sqrtf(ssa), EPSN);
    const float sp = 1.0f / fmaxf(sqrtf(ssp), EPSN);

    float oa[8], op[8];
    float s1p = 0.f, s2p = 0.f, s1a = 0.f, s2a = 0.f, pos = 0.f;
#pragma unroll
    for (int j = 0; j < 8; ++j) {
        oa[j] = va[j] * sa;
        op[j] = vp[j] * sp;
        s1p += op[j]; s2p += op[j] * op[j];
        s1a += oa[j]; s2a += oa[j] * oa[j];
        const float u = oa[j] - op[j] + EPSP;
        pos += u * u;
    }

    uint64_t pka = 0, pkp = 0;
#pragma unroll
    for (int j = 0; j < 8; ++j) {
        int qa = (int)rintf(oa[j] * QS);
        int qp = (int)rintf(op[j] * QS);
        qa = qa > 127 ? 127 : (qa < -127 ? -127 : qa);
        qp = qp > 127 ? 127 : (qp < -127 ? -127 : qp);
        pka |= (uint64_t)(uint8_t)qa << (8 * j);
        pkp |= (uint64_t)(uint8_t)qp << (8 * j);
    }
    *(uint64_t*)(a_i8 + (size_t)i * Dn + lane * 8) = pka;
    *(uint64_t*)(p_i8 + (size_t)i * Dn + lane * 8) = pkp;

#pragma unroll
    for (int m = 1; m < 64; m <<= 1) {
        s1p += __shfl_xor(s1p, m);
        s2p += __shfl_xor(s2p, m);
        s1a += __shfl_xor(s1a, m);
        s2a += __shfl_xor(s2a, m);
        pos += __shfl_xor(pos, m);
    }
    if (lane == 0) {
        cterm[i] = -s2p + 2.0f * EPSP * s1p;
        rowconst[i] = pos - s2a - 2.0f * EPSP * s1a
                      - (float)Dn * EPSP * EPSP + MARG;
        rowmax[i] = 0u;              // atomicMax identity (poisoned otherwise)
    }
}

// ---------------------------------------------------------------------------
// K2: i8 MFMA GEMM, 256^2 tile, 4-slot LDS ring (stage-ahead 3), register
// fragment prefetch one tile ahead, counted vmcnt, swapped operands (acc =
// C^T: j in-lane, i across lanes), fused per-i max epilogue.
// ---------------------------------------------------------------------------
#define READ_FRAGS(AF, BF, SLOT)                                             \
  {                                                                          \
    const uint8_t* pa_ = &As[(SLOT)][aOff];                                  \
    const uint8_t* pb_ = &Bs[(SLOT)][bOff];                                  \
    BF[0] = *(const int4v*)(pb_ + 0 * 1024);                                 \
    BF[1] = *(const int4v*)(pb_ + 1 * 1024);                                 \
    BF[2] = *(const int4v*)(pb_ + 2 * 1024);                                 \
    BF[3] = *(const int4v*)(pb_ + 3 * 1024);                                 \
    AF[0] = *(const int4v*)(pa_ + 0 * 1024);                                 \
    AF[1] = *(const int4v*)(pa_ + 1 * 1024);                                 \
    AF[2] = *(const int4v*)(pa_ + 2 * 1024);                                 \
    AF[3] = *(const int4v*)(pa_ + 3 * 1024);                                 \
    AF[4] = *(const int4v*)(pa_ + 4 * 1024);                                 \
    AF[5] = *(const int4v*)(pa_ + 5 * 1024);                                 \
    AF[6] = *(const int4v*)(pa_ + 6 * 1024);                                 \
    AF[7] = *(const int4v*)(pa_ + 7 * 1024);                                 \
  }

// One K-tile: (1) lgkm(0) certifies CUR frags (prefetched last tile),
// (2) prefetch NXT frags from slot (KT+1)&3, (3) stage slot (KT+3)&3,
// (4) 32 MFMAs on CUR, (5) counted vmem drain, (6) barrier.
#define TILE_BODY(CAF, CBF, NAF, NBF, KT)                                    \
  {                                                                          \
    asm volatile("s_waitcnt lgkmcnt(0)" ::: "memory");                       \
    __builtin_amdgcn_sched_barrier(0); /* rule 18: MFMA not above wait */    \
    if ((KT) + 1 < NKT) READ_FRAGS(NAF, NBF, ((KT) + 1) & 3);                \
    __builtin_amdgcn_sched_barrier(0); /* reads issue before MFMAs */        \
    if ((KT) + 3 < NKT) {                                                    \
      stage1(((KT) + 3) & 3, ((KT) + 3) * TKB, 0);                           \
      stage1(((KT) + 3) & 3, ((KT) + 3) * TKB, 1);                           \
      stage1(((KT) + 3) & 3, ((KT) + 3) * TKB, 2);                           \
      stage1(((KT) + 3) & 3, ((KT) + 3) * TKB, 3);                           \
    }                                                                        \
    __builtin_amdgcn_sched_barrier(0);                                       \
    __builtin_amdgcn_s_setprio(1);                                           \
    _Pragma("unroll")                                                        \
    for (int mt_ = 0; mt_ < 8; ++mt_) {                                      \
      _Pragma("unroll")                                                      \
      for (int nt_ = 0; nt_ < 4; ++nt_)                                      \
        acc[mt_][nt_] = __builtin_amdgcn_mfma_i32_16x16x64_i8(               \
            CAF[mt_], CBF[nt_], acc[mt_][nt_], 0, 0, 0);                     \
    }                                                                        \
    __builtin_amdgcn_s_setprio(0);                                           \
    if ((KT) + 3 < NKT)                                                      \
      asm volatile("s_waitcnt vmcnt(4)" ::: "memory");                       \
    else if ((KT) + 3 == NKT)                                                \
      asm volatile("s_waitcnt vmcnt(0)" ::: "memory");                       \
    if ((KT) + 1 < NKT) __builtin_amdgcn_s_barrier();                        \
  }

__global__ __launch_bounds__(512, 2) void k_gemm_argmax(
    const uint8_t* __restrict__ a_i8, const uint8_t* __restrict__ p_i8,
    const float* __restrict__ cterm,
    unsigned* __restrict__ rowmax)
{
    __shared__ __align__(16) uint8_t As[4][256 * TKB];   // 64 KB, p rows (j)
    __shared__ __align__(16) uint8_t Bs[4][256 * TKB];   // 64 KB, a rows (i)
    __shared__ unsigned smx[2][256];                     // wr-half combine

    const int t = threadIdx.x;          // 0..511
    const int wave = t >> 6;            // 0..7
    const int lane = t & 63;
    const int q = lane >> 4;            // 0..3  (k-chunk; C/D row = q*4+v)
    const int m16 = lane & 15;          // 0..15 (C/D col)
    const int wr = wave >> 2;           // j half (0..1)
    const int wc = wave & 3;            // i quarter (0..3)
    const int j0 = blockIdx.y * 256;    // p-row base
    const int i0 = blockIdx.x * 256;    // a-row base (rowmax index)

    // ---- staging: per K-tile = 4 insts/thread (A half0, A half1, B h0, B h1)
    // thread t covers chunk t of the half: row = half*128 + (t>>2), global
    // k-slot g = (t&3) ^ ((t>>3)&3)  (slot-XOR swizzle, BANK_CONFLICT=0).
    const int rr = t >> 2;                               // 0..127
    const int gg = ((t & 3) ^ ((t >> 3) & 3)) * 16;      // byte slot in k-tile
    const uint8_t* gA0 = p_i8 + (size_t)(j0 + rr) * Dn + gg;
    const uint8_t* gA1 = p_i8 + (size_t)(j0 + 128 + rr) * Dn + gg;
    const uint8_t* gB0 = a_i8 + (size_t)(i0 + rr) * Dn + gg;
    const uint8_t* gB1 = a_i8 + (size_t)(i0 + 128 + rr) * Dn + gg;
    const int ldsOff = wave * 1024;     // + HW lane*16; halves at +8192

    // ---- fragment read bases: slot = q ^ ((m16>>1)&3) (matches stage XOR)
    const int sl = (q ^ ((m16 >> 1) & 3)) * 16;
    const int aOff = (wr * 128 + m16) * TKB + sl;        // + mt*1024
    const int bOff = (wc * 64 + m16) * TKB + sl;         // + nt*1024

    auto stage1 = [&](int slot, int kb, int h) {
        switch (h) {
        case 0: async16(gA0 + kb, &As[slot][ldsOff]);        break;
        case 1: async16(gA1 + kb, &As[slot][8192 + ldsOff]); break;
        case 2: async16(gB0 + kb, &Bs[slot][ldsOff]);        break;
        case 3: async16(gB1 + kb, &Bs[slot][8192 + ldsOff]); break;
        }
    };

    int4v acc[8][4];
#pragma unroll
    for (int a = 0; a < 8; ++a)
#pragma unroll
        for (int b = 0; b < 4; ++b) acc[a][b] = (int4v){0, 0, 0, 0};

    int4v afA[8], bfA[4], afB[8], bfB[4];   // frag double-buffer (static idx)

    // prologue: stage tiles 0,1,2 (stage-ahead 3). Per-wave vmcnt(4) drains
    // this wave's stage(0)+stage(1); the barrier publishes slots 0,1.
#pragma unroll
    for (int h = 0; h < 4; ++h) stage1(0, 0, h);
#pragma unroll
    for (int h = 0; h < 4; ++h) stage1(1, TKB, h);
#pragma unroll
    for (int h = 0; h < 4; ++h) stage1(2, 2 * TKB, h);
    asm volatile("s_waitcnt vmcnt(4)" ::: "memory");
    __builtin_amdgcn_s_barrier();
    READ_FRAGS(afA, bfA, 0);             // tile 0 frags; drained at tile 0 top
    __builtin_amdgcn_sched_barrier(0);

    TILE_BODY(afA, bfA, afB, bfB, 0)
    TILE_BODY(afB, bfB, afA, bfA, 1)
    TILE_BODY(afA, bfA, afB, bfB, 2)
    TILE_BODY(afB, bfB, afA, bfA, 3)
    TILE_BODY(afA, bfA, afB, bfB, 4)
    TILE_BODY(afB, bfB, afA, bfA, 5)
    TILE_BODY(afA, bfA, afB, bfB, 6)
    TILE_BODY(afB, bfB, afA, bfA, 7)

    // ---- epilogue: acc[mt][nt][v] = idot(j, i) with
    //   j = j0 + wr*128 + mt*16 + q*4 + v   (32 in-lane candidates per nt)
    //   i = i0 + wc*64  + nt*16 + m16
    f32x4 cj[8];
#pragma unroll
    for (int mt = 0; mt < 8; ++mt)   // broadcast loads, L2-resident 32 KB
        cj[mt] = *(const f32x4*)(cterm + j0 + wr * 128 + mt * 16 + q * 4);

    unsigned kv[4];
    const bool diag = (i0 == j0);    // 32 of 1024 blocks
    if (!diag) {
#pragma unroll
        for (int nt = 0; nt < 4; ++nt) {
            float mx = -3.4e38f;
#pragma unroll
            for (int mt = 0; mt < 8; ++mt)
#pragma unroll
                for (int v = 0; v < 4; ++v)
                    mx = fmaxf(mx, ISQ * (float)acc[mt][nt][v] + cj[mt][v]);
            kv[nt] = key32(mx);
        }
    } else {
#pragma unroll
        for (int nt = 0; nt < 4; ++nt) {
            // j==i  <=>  mt*16+v == dtarget (at most one of the 32)
            const int dtarget = wc * 64 + nt * 16 + m16 - wr * 128 - q * 4;
            float mx = -3.4e38f;
#pragma unroll
            for (int mt = 0; mt < 8; ++mt)
#pragma unroll
                for (int v = 0; v < 4; ++v) {
                    const float sc = ISQ * (float)acc[mt][nt][v] + cj[mt][v];
                    mx = (mt * 16 + v == dtarget) ? mx : fmaxf(mx, sc);
                }
            kv[nt] = key32(mx);
        }
    }

    // combine the 4 q-groups (same i, different j): masks 16, 32
#pragma unroll
    for (int nt = 0; nt < 4; ++nt) {
#pragma unroll
        for (int msk = 16; msk < 64; msk <<= 1) {
            const unsigned o = (unsigned)__shfl_xor((int)kv[nt], msk);
            kv[nt] = o > kv[nt] ? o : kv[nt];
        }
    }
    if (lane < 16) {   // q==0 lanes hold the reduced keys
#pragma unroll
        for (int nt = 0; nt < 4; ++nt)
            smx[wr][wc * 64 + nt * 16 + m16] = kv[nt];
    }
    __syncthreads();
    if (t < 256) {
        const unsigned k0 = smx[0][t];
        const unsigned k1 = smx[1][t];
        // distributed per-row max: 32 blocks contend per address (order-
        // independent -> deterministic), 8192 addresses total.
        atomicMax(&rowmax[i0 + t], k0 > k1 ? k0 : k1);
    }
}

// ---------------------------------------------------------------------------
// K3: single block - loss = mean(relu(rowconst[i] + score_max[i])).
// Reads 64 KB; deterministic fixed-order sums.
// ---------------------------------------------------------------------------
__global__ __launch_bounds__(1024) void k_final(
    const unsigned* __restrict__ rowmax,
    const float* __restrict__ rowconst,
    float* __restrict__ out)
{
    __shared__ float smf[16];
    float s = 0.f;
    for (int k = threadIdx.x; k < Bn; k += 1024)
        s += fmaxf(rowconst[k] + unkey32(rowmax[k]), 0.f);
#pragma unroll
    for (int msk = 1; msk < 64; msk <<= 1) s += __shfl_xor(s, msk);
    if ((threadIdx.x & 63) == 0) smf[threadIdx.x >> 6] = s;
    __syncthreads();
    if (threadIdx.x == 0) {
        float tot = 0.f;
#pragma unroll
        for (int w = 0; w < 16; ++w) tot += smf[w];
        out[0] = tot * (1.0f / Bn);
    }
}

extern "C" void kernel_launch(void* const* d_in, const int* in_sizes, int n_in,
                              void* d_out, int out_size, void* d_ws, size_t ws_size,
                              hipStream_t stream)
{
    const float* x = (const float*)d_in[0];
    char* ws = (char*)d_ws;
    // workspace layout (bytes):
    uint8_t*  a_i8     = (uint8_t*)(ws + 0);         // 4 MB
    uint8_t*  p_i8     = (uint8_t*)(ws + 4194304);   // 4 MB
    float*    cterm    = (float*)(ws + 8388608);     // 32 KB
    float*    rowconst = (float*)(ws + 8421376);     // 32 KB
    unsigned* rowmax   = (unsigned*)(ws + 8454144);  // 32 KB (total ~8.5 MB)
    float*    out      = (float*)d_out;

    k_normalize<<<2048, 256, 0, stream>>>(x, a_i8, p_i8, cterm, rowconst, rowmax);
    k_gemm_argmax<<<dim3(Bn / 256, Bn / 256), 512, 0, stream>>>(
        a_i8, p_i8, cterm, rowmax);
    k_final<<<1, 1024, 0, stream>>>(rowmax, rowconst, out);
}